// Round 1
// 253.349 us; speedup vs baseline: 1.0121x; 1.0121x over previous
//
#include <hip/hip_runtime.h>
#include <math.h>
#include <stdint.h>

// ---------------- problem constants ----------------
#define NCHW    64                 // BS*CHS = 32*2 channels (= wave width!)
#define TLEN    131072             // samples per channel
#define IRLEN   32768
#define NTAPS   511
#define NBANDS  12
#define NOISELEN (IRLEN + NTAPS - 1)   // 33278

// ---------------- scan chunking ----------------
#define WUP     4096               // warm-up samples (accuracy-critical, keep)
#define CHK     512                // emit chunk per block
#define NBLK2   (TLEN / CHK)       // 256 blocks, 1/CU
#define NQ      (TLEN / 4)         // 32768 sample-quads
#define GRP     16                 // register prefetch group (quads)

#define K10     0.16609640474436813f   // log2(10)/20
#define DB2     6.0205999132796239f    // 20*log10(2)

__device__ __forceinline__ float fast_tanh(float z) {
    float az = fabsf(z);
    float e  = exp2f(az * 2.8853900817779268f);
    float r  = 1.0f - 2.0f / (e + 1.0f);
    return copysignf(r, z);
}

__device__ __forceinline__ float gain_db_one(float xs, float g, float thr,
                                             float q, float knee, float inv2k) {
    float y    = fast_tanh(xs * g);
    float a    = fabsf(y) + 1e-8f;
    float xdb  = __log2f(a) * DB2;
    float over = xdb - thr;
    float h    = over + 0.5f * knee;
    float gk   = q * h * h * inv2k;
    float t2   = 2.0f * over;
    return (t2 < -knee) ? 0.0f : ((t2 > knee) ? q * over : gk);
}

// static float4 component select (folds under unroll)
__device__ __forceinline__ float f4c(const float4& v, int s) {
    return s == 0 ? v.x : (s == 1 ? v.y : (s == 2 ? v.z : v.w));
}

// ---------- K1: gain computer + 4-step affine-min composition -------------
// Per sample t the scan step is p' = min(aa*p + A_t, ar*p + rho*A_t),
// A_t = (1-aa)*gain_db.  Composition of 4 steps is exactly
// p' = min_{m=0..4}( aa^(4-m) ar^m * p + I_m )  (concave PWL, monotone).
// k1 emits per (quad, ch): Q4 = (I0..I3), Q1 = I4, Pq = (A0..A3).
__global__ __launch_bounds__(256) void k1_gain(
    const float* __restrict__ x,
    const float* __restrict__ p_drive, const float* __restrict__ p_thr,
    const float* __restrict__ p_ratio, const float* __restrict__ p_knee,
    const float* __restrict__ p_atk,   const float* __restrict__ p_rel,
    const float* __restrict__ band_gains,
    float4* __restrict__ q4, float* __restrict__ q1, float4* __restrict__ pq,
    int* __restrict__ flag)
{
    if (blockIdx.x == 0 && threadIdx.x == 0) {
        int f = 0;
        #pragma unroll
        for (int b = 0; b < NBANDS; ++b) f |= (band_gains[b] != 0.0f) ? 1 : 0;
        *flag = f;
    }
    __shared__ float S[64 * 65];           // S[sample][ch], pitch 65 (2-way, free)
    int t0 = blockIdx.x * 64;
    int l  = threadIdx.x & 63;
    int w  = threadIdx.x >> 6;

    float g     = exp2f(p_drive[0] * K10);
    float thr   = p_thr[0];
    float knee  = fmaxf(p_knee[0], 1e-3f);
    float qr    = 1.0f / p_ratio[0] - 1.0f;
    float inv2k = 1.0f / (2.0f * knee);
    float aa    = expf(-1.0f / (48.0f * p_atk[0]));
    float ar    = expf(-1.0f / (48.0f * p_rel[0]));
    float omaa  = 1.0f - aa;
    float rho   = (1.0f - ar) / omaa;

    #pragma unroll
    for (int i = 0; i < 16; ++i) {
        int ch = w * 16 + i;
        float xv = x[(size_t)ch * TLEN + t0 + l];     // coalesced 256B/wave
        S[l * 65 + ch] = omaa * gain_db_one(xv, g, thr, qr, knee, inv2k);
    }
    __syncthreads();

    int ch = threadIdx.x & 63;
    int ql = threadIdx.x >> 6;
    #pragma unroll
    for (int k = 0; k < 4; ++k) {
        int qq = ql * 4 + k;                  // local quad (uniform per wave)
        int sb = qq * 4;
        float A0 = S[(sb + 0) * 65 + ch];
        float A1 = S[(sb + 1) * 65 + ch];
        float A2 = S[(sb + 2) * 65 + ch];
        float A3 = S[(sb + 3) * 65 + ch];
        float R0 = rho * A0, R1 = rho * A1, R2 = rho * A2, R3 = rho * A3;
        // DP over 4 steps; I[m] has slope aa^(j-m) ar^m
        float i0 = A0, i1 = R0;
        float n0 = fmaf(aa, i0, A1);
        float n1 = fminf(fmaf(aa, i1, A1), fmaf(ar, i0, R1));
        float n2 = fmaf(ar, i1, R1);
        float m0 = fmaf(aa, n0, A2);
        float m1 = fminf(fmaf(aa, n1, A2), fmaf(ar, n0, R2));
        float m2 = fminf(fmaf(aa, n2, A2), fmaf(ar, n1, R2));
        float m3 = fmaf(ar, n2, R2);
        float o0 = fmaf(aa, m0, A3);
        float o1 = fminf(fmaf(aa, m1, A3), fmaf(ar, m0, R3));
        float o2 = fminf(fmaf(aa, m2, A3), fmaf(ar, m1, R3));
        float o3 = fminf(fmaf(aa, m3, A3), fmaf(ar, m2, R3));
        float o4 = fmaf(ar, m3, R3);
        size_t gi = (size_t)(blockIdx.x * 16 + qq) * 64 + ch;  // 1KB/wave stores
        q4[gi] = make_float4(o0, o1, o2, o3);
        q1[gi] = o4;
        pq[gi] = make_float4(A0, A1, A2, A3);
    }
}

// one composed-quad chain step: 5 indep fma + 2 v_min3 (~16cy for 4 samples)
#define WSTEP(c4, c1s) { \
    float f0 = fmaf(s0, p, (c4).x); \
    float f1 = fmaf(s1, p, (c4).y); \
    float f2 = fmaf(s2, p, (c4).z); \
    float f3 = fmaf(s3, p, (c4).w); \
    float f4 = fmaf(s4, p, (c1s)); \
    p = fminf(fminf(fminf(f0, f1), f2), fminf(f3, f4)); \
}

// exact per-sample emit step (identical numerics to previous kernel)
#define ESTEP(Av, tl) { \
    float fa = fmaf(aa, p, (Av)); \
    float fr = fmaf(ar, p, rho * (Av)); \
    p = fminf(fa, fr); \
    Ssm[(tl) * 68 + lane] = p; \
}

// apply one (4ch x 4t) unit: smooth from LDS (b128 along ch, conflict-free),
// x preloaded in regs, float4 out/comp stores
#define APPLY(xv, tq, cq) { \
    float4 sm0 = *(const float4*)&Ssm[(4 * (tq) + 0) * 68 + (cq) * 4]; \
    float4 sm1 = *(const float4*)&Ssm[(4 * (tq) + 1) * 68 + (cq) * 4]; \
    float4 sm2 = *(const float4*)&Ssm[(4 * (tq) + 2) * 68 + (cq) * 4]; \
    float4 sm3 = *(const float4*)&Ssm[(4 * (tq) + 3) * 68 + (cq) * 4]; \
    _Pragma("unroll") \
    for (int cc = 0; cc < 4; ++cc) { \
        float c0 = fast_tanh(f4c(xv[cc], 0) * g) * exp2f((f4c(sm0, cc) + mk) * K10); \
        float c1 = fast_tanh(f4c(xv[cc], 1) * g) * exp2f((f4c(sm1, cc) + mk) * K10); \
        float c2 = fast_tanh(f4c(xv[cc], 2) * g) * exp2f((f4c(sm2, cc) + mk) * K10); \
        float c3 = fast_tanh(f4c(xv[cc], 3) * g) * exp2f((f4c(sm3, cc) + mk) * K10); \
        size_t oidx = (size_t)((cq) * 4 + cc) * TLEN + tb + 4 * (tq); \
        *(float4*)&out[oidx] = make_float4(dry * c0, dry * c1, dry * c2, dry * c3); \
        if (sflag) *(float4*)&comp[oidx] = make_float4(c0, c1, c2, c3); \
    } \
}

// ---------- K2: composed warm-up scan + fused emit/apply ------------------
// 256 blocks x 256 threads, 1 block/CU. Wave0 chains; all waves apply.
__global__ __launch_bounds__(256, 1) void k2_env(
    const float* __restrict__ x,
    const float4* __restrict__ q4, const float* __restrict__ q1,
    const float4* __restrict__ pq,
    const float* __restrict__ p_atk, const float* __restrict__ p_rel,
    const float* __restrict__ p_drive, const float* __restrict__ p_makeup,
    const float* __restrict__ p_mix, const int* __restrict__ flag,
    float* __restrict__ out, float* __restrict__ comp)
{
    __shared__ __attribute__((aligned(16))) float Ssm[128 * 68];  // 34.8 KB
    __shared__ int sflag;
    int tid = threadIdx.x;
    if (tid == 0) sflag = *flag;

    int b  = blockIdx.x;
    int j  = ((b & 7) << 5) | (b >> 3);    // XCD-contiguous chunk ranges
    int te = j * CHK;
    int t0 = (j >= WUP / CHK) ? te - WUP : 0;   // exact-from-zero for j<8
    int q0 = t0 >> 2, qe = te >> 2;
    int lane = tid & 63;                   // channel

    float aa  = expf(-1.0f / (48.0f * p_atk[0]));
    float ar  = expf(-1.0f / (48.0f * p_rel[0]));
    float rho = (1.0f - ar) / (1.0f - aa);
    float s0 = aa * aa * aa * aa, s1 = aa * aa * aa * ar, s2 = aa * aa * ar * ar,
          s3 = aa * ar * ar * ar, s4 = ar * ar * ar * ar;
    float g   = exp2f(p_drive[0] * K10);
    float mk  = p_makeup[0];
    float mix = p_mix[0];
    float dry = 1.0f - mix;

    float p = 0.0f;

    if (tid < 64 && qe > q0) {
        // warm-up: 32-quad ping-pong register prefetch (256cy chain covers L2 lat)
        float4 A4[GRP]; float A1v[GRP]; float4 B4[GRP]; float B1v[GRP];
        size_t base = (size_t)q0 * 64 + lane;
        #pragma unroll
        for (int u = 0; u < GRP; ++u) {
            A4[u]  = q4[base + (size_t)u * 64];
            A1v[u] = q1[base + (size_t)u * 64];
        }
        for (int gq = q0; gq < qe; gq += 2 * GRP) {    // nwq % 32 == 0 always
            size_t bb = (size_t)(gq + GRP) * 64 + lane;
            #pragma unroll
            for (int u = 0; u < GRP; ++u) {
                B4[u]  = q4[bb + (size_t)u * 64];
                B1v[u] = q1[bb + (size_t)u * 64];
            }
            #pragma unroll
            for (int u = 0; u < GRP; ++u) WSTEP(A4[u], A1v[u]);
            size_t ab = (size_t)(gq + 2 * GRP) * 64 + lane;  // overrun <= qe+15 < NQ: safe
            #pragma unroll
            for (int u = 0; u < GRP; ++u) {
                A4[u]  = q4[ab + (size_t)u * 64];
                A1v[u] = q1[ab + (size_t)u * 64];
            }
            #pragma unroll
            for (int u = 0; u < GRP; ++u) WSTEP(B4[u], B1v[u]);
        }
    }

    int tqa = tid & 31,         cqa = tid >> 5;          // unit tid
    int tqb = (tid + 256) & 31, cqb = (tid + 256) >> 5;  // unit tid+256

    for (int r = 0; r < 4; ++r) {          // 4 strips of 128 samples
        int tb = te + r * 128;
        float4 xva[4], xvb[4];             // x preload: in flight during emit
        #pragma unroll
        for (int cc = 0; cc < 4; ++cc) {
            xva[cc] = *(const float4*)&x[(size_t)(cqa * 4 + cc) * TLEN + tb + 4 * tqa];
            xvb[cc] = *(const float4*)&x[(size_t)(cqb * 4 + cc) * TLEN + tb + 4 * tqb];
        }
        if (tid < 64) {                    // wave0: exact per-sample emit
            float4 C4[GRP], D4[GRP];
            size_t eb = (size_t)(qe + r * 32) * 64 + lane;
            #pragma unroll
            for (int u = 0; u < GRP; ++u) C4[u] = pq[eb + (size_t)u * 64];
            #pragma unroll
            for (int u = 0; u < GRP; ++u) D4[u] = pq[eb + (size_t)(u + GRP) * 64];
            #pragma unroll
            for (int u = 0; u < GRP; ++u) {
                ESTEP(C4[u].x, u * 4 + 0); ESTEP(C4[u].y, u * 4 + 1);
                ESTEP(C4[u].z, u * 4 + 2); ESTEP(C4[u].w, u * 4 + 3);
            }
            #pragma unroll
            for (int u = 0; u < GRP; ++u) {
                int t4 = (u + GRP) * 4;
                ESTEP(D4[u].x, t4 + 0); ESTEP(D4[u].y, t4 + 1);
                ESTEP(D4[u].z, t4 + 2); ESTEP(D4[u].w, t4 + 3);
            }
        }
        __syncthreads();                   // smooth strip resident
        APPLY(xva, tqa, cqa);
        APPLY(xvb, tqb, cqb);
        __syncthreads();                   // strip consumed before next emit
    }
}

// ---------- K4 (guarded fallback): synthesize reverb IR -------------------
__global__ __launch_bounds__(256) void k4_ir(
    const float* __restrict__ noise, const float* __restrict__ fir,
    const float* __restrict__ gains, const float* __restrict__ decays,
    const int* __restrict__ flag, float* __restrict__ ir)
{
    __shared__ int sflag;
    if (threadIdx.x == 0) sflag = *flag;
    __syncthreads();
    if (!sflag) return;
    __shared__ float sf[NBANDS * NTAPS];
    for (int i = threadIdx.x; i < NBANDS * NTAPS; i += 256) sf[i] = fir[i];
    __syncthreads();
    size_t total  = (size_t)NCHW * IRLEN;
    size_t stride = (size_t)gridDim.x * 256;
    for (size_t idx = blockIdx.x * 256 + threadIdx.x; idx < total; idx += stride) {
        int nch = (int)(idx >> 15);
        int n   = (int)(idx & (IRLEN - 1));
        float tl  = n * (1.0f / (IRLEN - 1));
        float acc = 0.0f;
        for (int bb = 0; bb < NBANDS; ++bb) {
            float gb = gains[bb];
            if (gb == 0.0f) continue;
            float env = expf(-(decays[bb] * 10.0f + 1.0f) * tl) * gb;
            const float* np_ = noise + ((size_t)nch * NBANDS + bb) * NOISELEN + n;
            const float* fb  = sf + bb * NTAPS;
            float s = 0.0f;
            for (int k = 0; k < NTAPS; ++k) s = fmaf(np_[k], fb[k], s);
            acc = fmaf(env, s, acc);
        }
        ir[idx] = acc * (1.0f / NBANDS);
    }
}

// ---------- K5 (guarded fallback): wet convolution + mix ------------------
__global__ __launch_bounds__(256) void k5_wet(
    const float* __restrict__ comp, const float* __restrict__ ir,
    const float* __restrict__ p_mix, const int* __restrict__ flag,
    float* __restrict__ out)
{
    __shared__ int sflag;
    if (threadIdx.x == 0) sflag = *flag;
    __syncthreads();
    if (!sflag) return;
    float mix = p_mix[0];
    size_t total  = (size_t)NCHW * TLEN;
    size_t stride = (size_t)gridDim.x * 256;
    for (size_t idx = blockIdx.x * 256 + threadIdx.x; idx < total; idx += stride) {
        int nch = (int)(idx >> 17);
        int t   = (int)(idx & (TLEN - 1));
        const float* c   = comp + (size_t)nch * TLEN;
        const float* irp = ir + (size_t)nch * IRLEN;
        int kmax = (t < IRLEN - 1) ? t : (IRLEN - 1);
        float s = 0.0f;
        for (int k = 0; k <= kmax; ++k) s = fmaf(irp[k], c[t - k], s);
        out[idx] += mix * s;
    }
}

// ---------- host-side launch ----------------------------------------------
extern "C" void kernel_launch(void* const* d_in, const int* in_sizes, int n_in,
                              void* d_out, int out_size, void* d_ws, size_t ws_size,
                              hipStream_t stream)
{
    const float* x      = (const float*)d_in[0];
    const float* drive  = (const float*)d_in[1];
    const float* thr    = (const float*)d_in[2];
    const float* ratio  = (const float*)d_in[3];
    const float* atk    = (const float*)d_in[4];
    const float* rel    = (const float*)d_in[5];
    const float* knee   = (const float*)d_in[6];
    const float* makeup = (const float*)d_in[7];
    const float* mix    = (const float*)d_in[8];
    const float* bg     = (const float*)d_in[9];
    const float* bd     = (const float*)d_in[10];
    const float* noise  = (const float*)d_in[11];
    const float* fir    = (const float*)d_in[12];
    float* out = (float*)d_out;

    // ws: [flag 16B][Q4 33.55MB][Q1 8.39MB][Pq 33.55MB][comp 33.55MB][ir 8.39MB]
    char*  w    = (char*)d_ws;
    int*   flag = (int*)w;
    float* q4f  = (float*)(w + 16);
    float* q1f  = q4f + (size_t)NQ * 256;
    float* pqf  = q1f + (size_t)NQ * 64;
    float* cmp  = pqf + (size_t)NQ * 256;
    float* ir   = cmp + (size_t)NCHW * TLEN;

    k1_gain<<<TLEN / 64, 256, 0, stream>>>(x, drive, thr, ratio, knee, atk, rel,
                                           bg, (float4*)q4f, q1f, (float4*)pqf, flag);
    k2_env<<<NBLK2, 256, 0, stream>>>(x, (const float4*)q4f, q1f, (const float4*)pqf,
                                      atk, rel, drive, makeup, mix, flag, out, cmp);
    k4_ir<<<256, 256, 0, stream>>>(noise, fir, bg, bd, flag, ir);
    k5_wet<<<256, 256, 0, stream>>>(cmp, ir, mix, flag, out);
}